// Round 1
// baseline (282.402 us; speedup 1.0000x reference)
//
#include <hip/hip_runtime.h>
#include <math.h>

#define NN 10000
#define NE 100000
#define BN_EPS 1e-5f

// ---------------------------------------------------------------------------
// K1: layer-0 node kernel.
//  G0[n, k*32+o] = sum_i x[n,i]*w0[(i*32+o)*8+k]   (k<8)
//  G0[n, 256+o]  = sum_i x[n,i]*b0[i*32+o]         (bias fold, "k=8")
//  h0[n, o]      = sum_i x[n,i]*root0[i*32+o] + bias0[o]
//  block 0: zero out + BN stat accumulators; block 1: transpose head weights.
// ---------------------------------------------------------------------------
__global__ __launch_bounds__(256) void k_node0(
    const float* __restrict__ x, const float* __restrict__ w0,
    const float* __restrict__ b0, const float* __restrict__ root0,
    const float* __restrict__ bias0,
    float* __restrict__ G0, float* __restrict__ h0,
    float* __restrict__ st0, float* __restrict__ st1, float* __restrict__ outz,
    const float* __restrict__ s_w, const float* __restrict__ t_w,
    float* __restrict__ wstT)
{
  __shared__ float wT[16 * 320];
  int tid = threadIdx.x;
  for (int idx = tid; idx < 16 * 320; idx += 256) {
    int i = idx / 320, cc = idx - i * 320;
    float v;
    if (cc < 256)      { int k = cc >> 5, o = cc & 31; v = w0[(i * 32 + o) * 8 + k]; }
    else if (cc < 288) { v = b0[i * 32 + (cc & 31)]; }
    else               { v = root0[i * 32 + (cc - 288)]; }
    wT[idx] = v;
  }
  __syncthreads();

  int lane = tid & 63, wv = tid >> 6;
  for (int n = blockIdx.x * 4 + wv; n < NN; n += gridDim.x * 4) {
    const float* xp = x + n * 16;
    float xr[16];
#pragma unroll
    for (int j = 0; j < 16; ++j) xr[j] = xp[j];
    float a0 = 0.f, a1 = 0.f, a2 = 0.f, a3 = 0.f, a4 = 0.f;
#pragma unroll
    for (int i = 0; i < 16; ++i) {
      const float* wr = wT + i * 320;
      float4 w4 = *(const float4*)(wr + 4 * lane);
      float xi = xr[i];
      a0 = fmaf(xi, w4.x, a0); a1 = fmaf(xi, w4.y, a1);
      a2 = fmaf(xi, w4.z, a2); a3 = fmaf(xi, w4.w, a3);
      a4 = fmaf(xi, wr[256 + lane], a4);
    }
    *((float4*)(G0 + n * 288 + 4 * lane)) = make_float4(a0, a1, a2, a3);
    if (lane < 32) G0[n * 288 + 256 + lane] = a4;
    else           h0[n * 32 + (lane - 32)] = a4 + bias0[lane - 32];
  }

  if (blockIdx.x == 0) {
    for (int i = tid; i < 64 * 128; i += 256) outz[i] = 0.f;
    if (tid < 64)  st0[tid] = 0.f;
    if (tid < 128) st1[tid] = 0.f;
  }
  if (blockIdx.x == 1) {
    // wstT[i*256 + o]: o<128 -> s_w[o,i]; o>=128 -> t_w[o-128,i]
    for (int idx = tid; idx < 64 * 256; idx += 256) {
      int i = idx >> 8, o = idx & 255;
      wstT[idx] = (o < 128) ? s_w[o * 64 + i] : t_w[(o - 128) * 64 + i];
    }
  }
}

// ---------------------------------------------------------------------------
// K2: layer-0 edge kernel. Half-wave (32 lanes) per edge.
//  msg[o] = G0[src,256+o] + sum_k ea[e,k]*G0[src,k*32+o];  atomic into h0[dst].
// ---------------------------------------------------------------------------
__global__ __launch_bounds__(256) void k_edge0(
    const int* __restrict__ ei, const float* __restrict__ ea,
    const float* __restrict__ G0, float* __restrict__ h0)
{
  int tid = threadIdx.x;
  int e = blockIdx.x * 8 + (tid >> 5);
  if (e >= NE) return;
  int o = tid & 31;
  int src = ei[e], dst = ei[NE + e];
  const float* gr = G0 + src * 288;
  const float* er = ea + e * 8;
  float m = gr[256 + o];
#pragma unroll
  for (int k = 0; k < 8; ++k) m = fmaf(er[k], gr[k * 32 + o], m);
  unsafeAtomicAdd(&h0[dst * 32 + o], m);
}

// ---------------------------------------------------------------------------
// K3/K6: per-column sum & sumsq over N rows (BN stats), atomic partials.
// ---------------------------------------------------------------------------
template <int C>
__global__ __launch_bounds__(256) void k_stats(
    const float* __restrict__ h, float* __restrict__ st)
{
  const int RPB = 256 / C;
  int tid = threadIdx.x;
  int col = tid % C, rg = tid / C;
  float s1 = 0.f, s2 = 0.f;
  int step = gridDim.x * RPB;
  for (int n = blockIdx.x * RPB + rg; n < NN; n += step) {
    float v = h[n * C + col];
    s1 += v; s2 += v * v;
  }
  __shared__ float l1[256], l2[256];
  l1[tid] = s1; l2[tid] = s2;
  __syncthreads();
  if (tid < C) {
    for (int r = 1; r < RPB; ++r) { s1 += l1[r * C + tid]; s2 += l2[r * C + tid]; }
    unsafeAtomicAdd(&st[tid], s1);
    unsafeAtomicAdd(&st[C + tid], s2);
  }
}

// ---------------------------------------------------------------------------
// K4: BN0-apply + ReLU fused with layer-1 node kernel.
//  x1 = relu(bn(h0));  G1[n, k*64+o] (k<8), G1[n,512+o] = bias fold,
//  h1[n,o] = x1@root1 + bias1.  Weights staged in two 40KB LDS halves.
// ---------------------------------------------------------------------------
__global__ __launch_bounds__(256) void k_node1(
    const float* __restrict__ h0, const float* __restrict__ st0,
    const float* __restrict__ g0, const float* __restrict__ be0,
    const float* __restrict__ w1, const float* __restrict__ b1,
    const float* __restrict__ root1, const float* __restrict__ bias1,
    float* __restrict__ G1, float* __restrict__ h1)
{
  __shared__ float wT[32 * 320];
  __shared__ float bns[32], bnsh[32];
  int tid = threadIdx.x;
  if (tid < 32) {
    float mu  = st0[tid] * (1.0f / NN);
    float var = st0[32 + tid] * (1.0f / NN) - mu * mu;
    float sc  = g0[tid] * rsqrtf(var + BN_EPS);
    bns[tid]  = sc;
    bnsh[tid] = be0[tid] - mu * sc;
  }
  int lane = tid & 63, wv = tid >> 6;

  for (int half = 0; half < 2; ++half) {
    __syncthreads();
    for (int idx = tid; idx < 32 * 320; idx += 256) {
      int i = idx / 320, cc = idx - i * 320;
      int C = half * 320 + cc;
      float v;
      if (C < 512)      { int k = C >> 6, o = C & 63; v = w1[(i * 64 + o) * 8 + k]; }
      else if (C < 576) { v = b1[i * 64 + (C & 63)]; }
      else              { v = root1[i * 64 + (C - 576)]; }
      wT[idx] = v;
    }
    __syncthreads();

    for (int n = blockIdx.x * 4 + wv; n < NN; n += gridDim.x * 4) {
      int c = lane & 31;
      float x1 = fmaxf(fmaf(h0[n * 32 + c], bns[c], bnsh[c]), 0.0f);
      float a0 = 0.f, a1 = 0.f, a2 = 0.f, a3 = 0.f, a4 = 0.f;
#pragma unroll
      for (int i = 0; i < 32; ++i) {
        float xi = __shfl(x1, i);
        const float* wr = wT + i * 320;
        float4 w4 = *(const float4*)(wr + 4 * lane);
        a0 = fmaf(xi, w4.x, a0); a1 = fmaf(xi, w4.y, a1);
        a2 = fmaf(xi, w4.z, a2); a3 = fmaf(xi, w4.w, a3);
        a4 = fmaf(xi, wr[256 + lane], a4);
      }
      *((float4*)(G1 + n * 576 + half * 320 + 4 * lane)) = make_float4(a0, a1, a2, a3);
      int Cs = half * 320 + 256 + lane;
      if (Cs < 576) G1[n * 576 + Cs] = a4;
      else          h1[n * 64 + (Cs - 576)] = a4 + bias1[Cs - 576];
    }
  }
}

// ---------------------------------------------------------------------------
// K5: layer-1 edge kernel. One wave (64 lanes) per edge.
// ---------------------------------------------------------------------------
__global__ __launch_bounds__(256) void k_edge1(
    const int* __restrict__ ei, const float* __restrict__ ea,
    const float* __restrict__ G1, float* __restrict__ h1)
{
  int tid = threadIdx.x;
  int e = blockIdx.x * 4 + (tid >> 6);
  if (e >= NE) return;
  int o = tid & 63;
  int src = ei[e], dst = ei[NE + e];
  const float* gr = G1 + src * 576;
  const float* er = ea + e * 8;
  float m = gr[512 + o];
#pragma unroll
  for (int k = 0; k < 8; ++k) m = fmaf(er[k], gr[k * 64 + o], m);
  unsafeAtomicAdd(&h1[dst * 64 + o], m);
}

// ---------------------------------------------------------------------------
// K7: BN1-apply + ReLU + s/t heads + f = sigmoid(-s)*tanh(t) + batch segsum.
//  One wave per node. wstT ([i][o], o<128 s / o>=128 t) staged to 64KB LDS.
//  Lanes 0..31 own s outputs {4l..4l+3}; lanes 32..63 own t outputs.
// ---------------------------------------------------------------------------
__global__ __launch_bounds__(256) void k_head(
    const float* __restrict__ h1, const float* __restrict__ st1,
    const float* __restrict__ g1, const float* __restrict__ be1,
    const float* __restrict__ wstT, const float* __restrict__ s_b,
    const float* __restrict__ t_b, const int* __restrict__ batch,
    float* __restrict__ out)
{
  __shared__ float wst[64 * 256];
  int tid = threadIdx.x;
  for (int idx = tid; idx < 64 * 256; idx += 256) wst[idx] = wstT[idx];

  int lane = tid & 63, wv = tid >> 6;
  float mu  = st1[lane] * (1.0f / NN);
  float var = st1[64 + lane] * (1.0f / NN) - mu * mu;
  float sc  = g1[lane] * rsqrtf(var + BN_EPS);
  float sh  = be1[lane] - mu * sc;

  float sb0, sb1, sb2, sb3;
  if (lane < 32) {
    sb0 = s_b[4 * lane]; sb1 = s_b[4 * lane + 1];
    sb2 = s_b[4 * lane + 2]; sb3 = s_b[4 * lane + 3];
  } else {
    int o = 4 * (lane - 32);
    sb0 = t_b[o]; sb1 = t_b[o + 1]; sb2 = t_b[o + 2]; sb3 = t_b[o + 3];
  }
  __syncthreads();

  for (int n = blockIdx.x * 4 + wv; n < NN; n += gridDim.x * 4) {
    float x2 = fmaxf(fmaf(h1[n * 64 + lane], sc, sh), 0.0f);
    float a0 = 0.f, a1 = 0.f, a2 = 0.f, a3 = 0.f;
#pragma unroll
    for (int i = 0; i < 64; ++i) {
      float xi = __shfl(x2, i);
      float4 w4 = *(const float4*)(wst + i * 256 + 4 * lane);
      a0 = fmaf(xi, w4.x, a0); a1 = fmaf(xi, w4.y, a1);
      a2 = fmaf(xi, w4.z, a2); a3 = fmaf(xi, w4.w, a3);
    }
    float v0 = a0 + sb0, v1 = a1 + sb1, v2 = a2 + sb2, v3 = a3 + sb3;
    if (lane < 32) {  // s side: clip to [-30, 30]
      v0 = fminf(30.f, fmaxf(-30.f, v0));
      v1 = fminf(30.f, fmaxf(-30.f, v1));
      v2 = fminf(30.f, fmaxf(-30.f, v2));
      v3 = fminf(30.f, fmaxf(-30.f, v3));
    }
    float t0 = __shfl_xor(v0, 32), t1 = __shfl_xor(v1, 32);
    float t2 = __shfl_xor(v2, 32), t3 = __shfl_xor(v3, 32);
    if (lane < 32) {
      int b = batch[n];
      float f0 = tanhf(t0) / (1.f + expf(v0));
      float f1 = tanhf(t1) / (1.f + expf(v1));
      float f2 = tanhf(t2) / (1.f + expf(v2));
      float f3 = tanhf(t3) / (1.f + expf(v3));
      unsafeAtomicAdd(&out[b * 128 + 4 * lane + 0], f0);
      unsafeAtomicAdd(&out[b * 128 + 4 * lane + 1], f1);
      unsafeAtomicAdd(&out[b * 128 + 4 * lane + 2], f2);
      unsafeAtomicAdd(&out[b * 128 + 4 * lane + 3], f3);
    }
  }
}

// ---------------------------------------------------------------------------
extern "C" void kernel_launch(void* const* d_in, const int* in_sizes, int n_in,
                              void* d_out, int out_size, void* d_ws, size_t ws_size,
                              hipStream_t stream)
{
  const float* x     = (const float*)d_in[0];
  const int*   ei    = (const int*)d_in[1];
  const float* ea    = (const float*)d_in[2];
  const int*   batch = (const int*)d_in[3];
  // d_in[4] edge_batch: unused by the reference
  const float* w0    = (const float*)d_in[5];
  const float* b0    = (const float*)d_in[6];
  const float* root0 = (const float*)d_in[7];
  const float* bias0 = (const float*)d_in[8];
  const float* g0    = (const float*)d_in[9];
  const float* be0   = (const float*)d_in[10];
  const float* w1    = (const float*)d_in[11];
  const float* b1    = (const float*)d_in[12];
  const float* root1 = (const float*)d_in[13];
  const float* bias1 = (const float*)d_in[14];
  const float* g1    = (const float*)d_in[15];
  const float* be1   = (const float*)d_in[16];
  const float* s_w   = (const float*)d_in[17];
  const float* s_b   = (const float*)d_in[18];
  const float* t_w   = (const float*)d_in[19];
  const float* t_b   = (const float*)d_in[20];
  float* out = (float*)d_out;

  float* ws   = (float*)d_ws;
  float* G0   = ws;  ws += 2880000;   // N*288
  float* G1   = ws;  ws += 5760000;   // N*576
  float* h0   = ws;  ws += 320000;    // N*32
  float* h1   = ws;  ws += 640000;    // N*64
  float* st0  = ws;  ws += 64;
  float* st1  = ws;  ws += 128;
  float* wstT = ws;  ws += 16384;     // 64x256 transposed head weights

  hipLaunchKernelGGL(k_node0, dim3(256), dim3(256), 0, stream,
                     x, w0, b0, root0, bias0, G0, h0, st0, st1, out, s_w, t_w, wstT);
  hipLaunchKernelGGL(k_edge0, dim3((NE + 7) / 8), dim3(256), 0, stream, ei, ea, G0, h0);
  hipLaunchKernelGGL(k_stats<32>, dim3(64), dim3(256), 0, stream, h0, st0);
  hipLaunchKernelGGL(k_node1, dim3(512), dim3(256), 0, stream,
                     h0, st0, g0, be0, w1, b1, root1, bias1, G1, h1);
  hipLaunchKernelGGL(k_edge1, dim3((NE + 3) / 4), dim3(256), 0, stream, ei, ea, G1, h1);
  hipLaunchKernelGGL(k_stats<64>, dim3(128), dim3(256), 0, stream, h1, st1);
  hipLaunchKernelGGL(k_head, dim3(256), dim3(256), 0, stream,
                     h1, st1, g1, be1, wstT, s_b, t_b, batch, out);
}

// Round 2
// 241.887 us; speedup vs baseline: 1.1675x; 1.1675x over previous
//
#include <hip/hip_runtime.h>
#include <math.h>

#define NN 10000
#define NE 100000
#define BN_EPS 1e-5f

// ---------------------------------------------------------------------------
// K1: layer-0 node kernel.
//  G0[n, k*32+o] = sum_i x[n,i]*w0[(i*32+o)*8+k]   (k<8)
//  G0[n, 256+o]  = sum_i x[n,i]*b0[i*32+o]         (bias fold, "k=8")
//  h0[n, o]      = sum_i x[n,i]*root0[i*32+o] + bias0[o]
//  block 0: zero out + BN stat accumulators; block 1: transpose head weights.
// ---------------------------------------------------------------------------
__global__ __launch_bounds__(256) void k_node0(
    const float* __restrict__ x, const float* __restrict__ w0,
    const float* __restrict__ b0, const float* __restrict__ root0,
    const float* __restrict__ bias0,
    float* __restrict__ G0, float* __restrict__ h0,
    float* __restrict__ st0, float* __restrict__ st1, float* __restrict__ outz,
    const float* __restrict__ s_w, const float* __restrict__ t_w,
    float* __restrict__ wstT)
{
  __shared__ float wT[16 * 320];
  int tid = threadIdx.x;
  for (int idx = tid; idx < 16 * 320; idx += 256) {
    int i = idx / 320, cc = idx - i * 320;
    float v;
    if (cc < 256)      { int k = cc >> 5, o = cc & 31; v = w0[(i * 32 + o) * 8 + k]; }
    else if (cc < 288) { v = b0[i * 32 + (cc & 31)]; }
    else               { v = root0[i * 32 + (cc - 288)]; }
    wT[idx] = v;
  }
  __syncthreads();

  int lane = tid & 63, wv = tid >> 6;
  for (int n = blockIdx.x * 4 + wv; n < NN; n += gridDim.x * 4) {
    const float* xp = x + n * 16;
    float xr[16];
#pragma unroll
    for (int j = 0; j < 16; ++j) xr[j] = xp[j];
    float a0 = 0.f, a1 = 0.f, a2 = 0.f, a3 = 0.f, a4 = 0.f;
#pragma unroll
    for (int i = 0; i < 16; ++i) {
      const float* wr = wT + i * 320;
      float4 w4 = *(const float4*)(wr + 4 * lane);
      float xi = xr[i];
      a0 = fmaf(xi, w4.x, a0); a1 = fmaf(xi, w4.y, a1);
      a2 = fmaf(xi, w4.z, a2); a3 = fmaf(xi, w4.w, a3);
      a4 = fmaf(xi, wr[256 + lane], a4);
    }
    *((float4*)(G0 + n * 288 + 4 * lane)) = make_float4(a0, a1, a2, a3);
    if (lane < 32) G0[n * 288 + 256 + lane] = a4;
    else           h0[n * 32 + (lane - 32)] = a4 + bias0[lane - 32];
  }

  if (blockIdx.x == 0) {
    for (int i = tid; i < 64 * 128; i += 256) outz[i] = 0.f;
    if (tid < 64)  st0[tid] = 0.f;
    if (tid < 128) st1[tid] = 0.f;
  }
  if (blockIdx.x == 1) {
    // wstT[i*256 + o]: o<128 -> s_w[o,i]; o>=128 -> t_w[o-128,i]
    for (int idx = tid; idx < 64 * 256; idx += 256) {
      int i = idx >> 8, o = idx & 255;
      wstT[idx] = (o < 128) ? s_w[o * 64 + i] : t_w[(o - 128) * 64 + i];
    }
  }
}

// ---------------------------------------------------------------------------
// K2: layer-0 edge kernel. Half-wave (32 lanes) per edge.
// ---------------------------------------------------------------------------
__global__ __launch_bounds__(256) void k_edge0(
    const int* __restrict__ ei, const float* __restrict__ ea,
    const float* __restrict__ G0, float* __restrict__ h0)
{
  int tid = threadIdx.x;
  int e = blockIdx.x * 8 + (tid >> 5);
  if (e >= NE) return;
  int o = tid & 31;
  int src = ei[e], dst = ei[NE + e];
  const float* gr = G0 + src * 288;
  const float* er = ea + e * 8;
  float m = gr[256 + o];
#pragma unroll
  for (int k = 0; k < 8; ++k) m = fmaf(er[k], gr[k * 32 + o], m);
  unsafeAtomicAdd(&h0[dst * 32 + o], m);
}

// ---------------------------------------------------------------------------
// K3/K6: per-column sum & sumsq over N rows (BN stats), atomic partials.
// ---------------------------------------------------------------------------
template <int C>
__global__ __launch_bounds__(256) void k_stats(
    const float* __restrict__ h, float* __restrict__ st)
{
  const int RPB = 256 / C;
  int tid = threadIdx.x;
  int col = tid % C, rg = tid / C;
  float s1 = 0.f, s2 = 0.f;
  int step = gridDim.x * RPB;
  for (int n = blockIdx.x * RPB + rg; n < NN; n += step) {
    float v = h[n * C + col];
    s1 += v; s2 += v * v;
  }
  __shared__ float l1[256], l2[256];
  l1[tid] = s1; l2[tid] = s2;
  __syncthreads();
  if (tid < C) {
    for (int r = 1; r < RPB; ++r) { s1 += l1[r * C + tid]; s2 += l2[r * C + tid]; }
    unsafeAtomicAdd(&st[tid], s1);
    unsafeAtomicAdd(&st[C + tid], s2);
  }
}

// ---------------------------------------------------------------------------
// K4: BN0-apply + ReLU fused with layer-1 node kernel.
// ---------------------------------------------------------------------------
__global__ __launch_bounds__(256) void k_node1(
    const float* __restrict__ h0, const float* __restrict__ st0,
    const float* __restrict__ g0, const float* __restrict__ be0,
    const float* __restrict__ w1, const float* __restrict__ b1,
    const float* __restrict__ root1, const float* __restrict__ bias1,
    float* __restrict__ G1, float* __restrict__ h1)
{
  __shared__ float wT[32 * 320];
  __shared__ float bns[32], bnsh[32];
  int tid = threadIdx.x;
  if (tid < 32) {
    float mu  = st0[tid] * (1.0f / NN);
    float var = st0[32 + tid] * (1.0f / NN) - mu * mu;
    float sc  = g0[tid] * rsqrtf(var + BN_EPS);
    bns[tid]  = sc;
    bnsh[tid] = be0[tid] - mu * sc;
  }
  int lane = tid & 63, wv = tid >> 6;

  for (int half = 0; half < 2; ++half) {
    __syncthreads();
    for (int idx = tid; idx < 32 * 320; idx += 256) {
      int i = idx / 320, cc = idx - i * 320;
      int C = half * 320 + cc;
      float v;
      if (C < 512)      { int k = C >> 6, o = C & 63; v = w1[(i * 64 + o) * 8 + k]; }
      else if (C < 576) { v = b1[i * 64 + (C & 63)]; }
      else              { v = root1[i * 64 + (C - 576)]; }
      wT[idx] = v;
    }
    __syncthreads();

    for (int n = blockIdx.x * 4 + wv; n < NN; n += gridDim.x * 4) {
      int c = lane & 31;
      float x1 = fmaxf(fmaf(h0[n * 32 + c], bns[c], bnsh[c]), 0.0f);
      float a0 = 0.f, a1 = 0.f, a2 = 0.f, a3 = 0.f, a4 = 0.f;
#pragma unroll
      for (int i = 0; i < 32; ++i) {
        float xi = __shfl(x1, i);
        const float* wr = wT + i * 320;
        float4 w4 = *(const float4*)(wr + 4 * lane);
        a0 = fmaf(xi, w4.x, a0); a1 = fmaf(xi, w4.y, a1);
        a2 = fmaf(xi, w4.z, a2); a3 = fmaf(xi, w4.w, a3);
        a4 = fmaf(xi, wr[256 + lane], a4);
      }
      *((float4*)(G1 + n * 576 + half * 320 + 4 * lane)) = make_float4(a0, a1, a2, a3);
      int Cs = half * 320 + 256 + lane;
      if (Cs < 576) G1[n * 576 + Cs] = a4;
      else          h1[n * 64 + (Cs - 576)] = a4 + bias1[Cs - 576];
    }
  }
}

// ---------------------------------------------------------------------------
// K5: layer-1 edge kernel. One wave (64 lanes) per edge.
// ---------------------------------------------------------------------------
__global__ __launch_bounds__(256) void k_edge1(
    const int* __restrict__ ei, const float* __restrict__ ea,
    const float* __restrict__ G1, float* __restrict__ h1)
{
  int tid = threadIdx.x;
  int e = blockIdx.x * 4 + (tid >> 6);
  if (e >= NE) return;
  int o = tid & 63;
  int src = ei[e], dst = ei[NE + e];
  const float* gr = G1 + src * 576;
  const float* er = ea + e * 8;
  float m = gr[512 + o];
#pragma unroll
  for (int k = 0; k < 8; ++k) m = fmaf(er[k], gr[k * 64 + o], m);
  unsafeAtomicAdd(&h1[dst * 64 + o], m);
}

// ---------------------------------------------------------------------------
// K6b: materialize x2 = relu(bn1(h1)), [N,64] fp32.  Memory-bound, ~5 MB.
// ---------------------------------------------------------------------------
__global__ __launch_bounds__(256) void k_x2(
    const float* __restrict__ h1, const float* __restrict__ st1,
    const float* __restrict__ g1, const float* __restrict__ be1,
    float* __restrict__ x2)
{
  __shared__ float sc[64], sh[64];
  int tid = threadIdx.x;
  if (tid < 64) {
    float mu  = st1[tid] * (1.0f / NN);
    float var = st1[64 + tid] * (1.0f / NN) - mu * mu;
    float s   = g1[tid] * rsqrtf(var + BN_EPS);
    sc[tid] = s;
    sh[tid] = be1[tid] - mu * s;
  }
  __syncthreads();
  const int NV = NN * 16;  // float4 count
  for (int i = blockIdx.x * 256 + tid; i < NV; i += gridDim.x * 256) {
    float4 v = ((const float4*)h1)[i];
    int c0 = (i * 4) & 63;
    v.x = fmaxf(fmaf(v.x, sc[c0],     sh[c0]),     0.f);
    v.y = fmaxf(fmaf(v.y, sc[c0 + 1], sh[c0 + 1]), 0.f);
    v.z = fmaxf(fmaf(v.z, sc[c0 + 2], sh[c0 + 2]), 0.f);
    v.w = fmaxf(fmaf(v.w, sc[c0 + 3], sh[c0 + 3]), 0.f);
    ((float4*)x2)[i] = v;
  }
}

// ---------------------------------------------------------------------------
// K7: head. Thread c (0..127 per 2-wave group) owns output column c: holds
//  s_w[:,c] and t_w[:,c] in 128 VGPRs (from pre-transposed wstT, coalesced).
//  Per node: 16 same-address dwordx4 broadcasts of the x2 row + 128 v_fmac.
//  No LDS, no shfl, no barrier. Sorted batch -> per-thread accumulator,
//  one atomic per batch boundary per thread.
//  Grid: 250 blocks x 40 nodes; group g = tid>>7 takes 20 contiguous nodes.
// ---------------------------------------------------------------------------
__global__ __launch_bounds__(256) void k_head(
    const float* __restrict__ x2, const float* __restrict__ wstT,
    const float* __restrict__ s_b, const float* __restrict__ t_b,
    const int* __restrict__ batch, float* __restrict__ out)
{
  int tid = threadIdx.x;
  int c = tid & 127, g = tid >> 7;
  int n0 = blockIdx.x * 40 + g * 20;
  int n1 = n0 + 20;
  if (n0 >= NN) return;
  if (n1 > NN) n1 = NN;

  float wsr[64], wtr[64];
#pragma unroll
  for (int k = 0; k < 64; ++k) {
    wsr[k] = wstT[k * 256 + c];
    wtr[k] = wstT[k * 256 + 128 + c];
  }
  float sb = s_b[c], tb = t_b[c];

  int bcur = batch[n0];
  float facc = 0.f;
  for (int n = n0; n < n1; ++n) {
    const float4* xr = (const float4*)(x2 + (size_t)n * 64);
    float as = 0.f, at = 0.f;
#pragma unroll
    for (int q = 0; q < 16; ++q) {
      float4 xv = xr[q];
      as = fmaf(xv.x, wsr[4 * q + 0], as); at = fmaf(xv.x, wtr[4 * q + 0], at);
      as = fmaf(xv.y, wsr[4 * q + 1], as); at = fmaf(xv.y, wtr[4 * q + 1], at);
      as = fmaf(xv.z, wsr[4 * q + 2], as); at = fmaf(xv.z, wtr[4 * q + 2], at);
      as = fmaf(xv.w, wsr[4 * q + 3], as); at = fmaf(xv.w, wtr[4 * q + 3], at);
    }
    float sv = fminf(30.f, fmaxf(-30.f, as + sb));
    float tv = at + tb;
    float f  = tanhf(tv) / (1.f + expf(sv));
    int b = batch[n];
    if (b != bcur) {
      unsafeAtomicAdd(&out[bcur * 128 + c], facc);
      bcur = b; facc = 0.f;
    }
    facc += f;
  }
  unsafeAtomicAdd(&out[bcur * 128 + c], facc);
}

// ---------------------------------------------------------------------------
extern "C" void kernel_launch(void* const* d_in, const int* in_sizes, int n_in,
                              void* d_out, int out_size, void* d_ws, size_t ws_size,
                              hipStream_t stream)
{
  const float* x     = (const float*)d_in[0];
  const int*   ei    = (const int*)d_in[1];
  const float* ea    = (const float*)d_in[2];
  const int*   batch = (const int*)d_in[3];
  // d_in[4] edge_batch: unused by the reference
  const float* w0    = (const float*)d_in[5];
  const float* b0    = (const float*)d_in[6];
  const float* root0 = (const float*)d_in[7];
  const float* bias0 = (const float*)d_in[8];
  const float* g0    = (const float*)d_in[9];
  const float* be0   = (const float*)d_in[10];
  const float* w1    = (const float*)d_in[11];
  const float* b1    = (const float*)d_in[12];
  const float* root1 = (const float*)d_in[13];
  const float* bias1 = (const float*)d_in[14];
  const float* g1    = (const float*)d_in[15];
  const float* be1   = (const float*)d_in[16];
  const float* s_w   = (const float*)d_in[17];
  const float* s_b   = (const float*)d_in[18];
  const float* t_w   = (const float*)d_in[19];
  const float* t_b   = (const float*)d_in[20];
  float* out = (float*)d_out;

  float* ws   = (float*)d_ws;
  float* G0   = ws;  ws += 2880000;   // N*288
  float* G1   = ws;  ws += 5760000;   // N*576
  float* h0   = ws;  ws += 320000;    // N*32
  float* h1   = ws;  ws += 640000;    // N*64
  float* st0  = ws;  ws += 64;
  float* st1  = ws;  ws += 128;
  float* wstT = ws;  ws += 16384;     // 64x256 transposed head weights
  float* x2   = ws;  ws += 640000;    // N*64 relu(bn1(h1))

  hipLaunchKernelGGL(k_node0, dim3(256), dim3(256), 0, stream,
                     x, w0, b0, root0, bias0, G0, h0, st0, st1, out, s_w, t_w, wstT);
  hipLaunchKernelGGL(k_edge0, dim3((NE + 7) / 8), dim3(256), 0, stream, ei, ea, G0, h0);
  hipLaunchKernelGGL(k_stats<32>, dim3(64), dim3(256), 0, stream, h0, st0);
  hipLaunchKernelGGL(k_node1, dim3(512), dim3(256), 0, stream,
                     h0, st0, g0, be0, w1, b1, root1, bias1, G1, h1);
  hipLaunchKernelGGL(k_edge1, dim3((NE + 3) / 4), dim3(256), 0, stream, ei, ea, G1, h1);
  hipLaunchKernelGGL(k_stats<64>, dim3(128), dim3(256), 0, stream, h1, st1);
  hipLaunchKernelGGL(k_x2, dim3(320), dim3(256), 0, stream, h1, st1, g1, be1, x2);
  hipLaunchKernelGGL(k_head, dim3(250), dim3(256), 0, stream,
                     x2, wstT, s_b, t_b, batch, out);
}

// Round 3
// 210.496 us; speedup vs baseline: 1.3416x; 1.1491x over previous
//
#include <hip/hip_runtime.h>
#include <math.h>

#define NN 10000
#define NE 100000
#define BN_EPS 1e-5f

// ---------------------------------------------------------------------------
// K0: prep. Pre-transpose weights into column-major-by-output layouts and
// zero the accumulators. Runs once, ~50K elements, trivial.
//  wT0[i*320+c]: c<256 -> w0[(i*32+(c&31))*8+(c>>5)]; c<288 -> b0; else root0
//  wT1[i*640+c]: c<512 -> w1[(i*64+(c&63))*8+(c>>6)]; c<576 -> b1; else root1
//  wstT[i*256+o]: o<128 -> s_w[o,i]; else t_w[o-128,i]
// ---------------------------------------------------------------------------
__global__ __launch_bounds__(256) void k_prep(
    const float* __restrict__ w0, const float* __restrict__ b0,
    const float* __restrict__ root0,
    const float* __restrict__ w1, const float* __restrict__ b1,
    const float* __restrict__ root1,
    const float* __restrict__ s_w, const float* __restrict__ t_w,
    float* __restrict__ wT0, float* __restrict__ wT1, float* __restrict__ wstT,
    float* __restrict__ st0, float* __restrict__ st1, float* __restrict__ out)
{
  int gid = blockIdx.x * 256 + threadIdx.x;
  int gsz = gridDim.x * 256;
  for (int idx = gid; idx < 16 * 320; idx += gsz) {
    int i = idx / 320, c = idx - i * 320;
    float v;
    if (c < 256)      v = w0[(i * 32 + (c & 31)) * 8 + (c >> 5)];
    else if (c < 288) v = b0[i * 32 + (c - 256)];
    else              v = root0[i * 32 + (c - 288)];
    wT0[idx] = v;
  }
  for (int idx = gid; idx < 32 * 640; idx += gsz) {
    int i = idx / 640, c = idx - i * 640;
    float v;
    if (c < 512)      v = w1[(i * 64 + (c & 63)) * 8 + (c >> 6)];
    else if (c < 576) v = b1[i * 64 + (c - 512)];
    else              v = root1[i * 64 + (c - 576)];
    wT1[idx] = v;
  }
  for (int idx = gid; idx < 64 * 256; idx += gsz) {
    int i = idx >> 8, o = idx & 255;
    wstT[idx] = (o < 128) ? s_w[o * 64 + i] : t_w[(o - 128) * 64 + i];
  }
  for (int idx = gid; idx < 64 * 128; idx += gsz) out[idx] = 0.f;
  if (gid < 64)  st0[gid] = 0.f;
  if (gid < 128) st1[gid] = 0.f;
}

// ---------------------------------------------------------------------------
// K1: layer-0 node kernel, register-column GEMV.
//  Thread c (0..319) owns output column c: 16 weight VGPRs from wT0
//  (coalesced). Per node: 4 same-address float4 broadcasts of x row + 16 fma.
//  c<288 -> G0 col; c>=288 -> h0 col (+bias0). 2 nodes/iter for ILP.
//  Grid: 500 blocks x 20 nodes = 10000 exactly.
// ---------------------------------------------------------------------------
__global__ __launch_bounds__(320) void k_node0(
    const float* __restrict__ x, const float* __restrict__ wT0,
    const float* __restrict__ bias0,
    float* __restrict__ G0, float* __restrict__ h0)
{
  int c = threadIdx.x;
  float wc[16];
#pragma unroll
  for (int i = 0; i < 16; ++i) wc[i] = wT0[i * 320 + c];
  float bi = (c >= 288) ? bias0[c - 288] : 0.f;

  int n0 = blockIdx.x * 20;
  for (int n = n0; n < n0 + 20; n += 2) {
    const float4* xa = (const float4*)(x + n * 16);
    float a0 = 0.f, a1 = 0.f;
#pragma unroll
    for (int q = 0; q < 4; ++q) {
      float4 v0 = xa[q], v1 = xa[q + 4];
      a0 = fmaf(v0.x, wc[4 * q + 0], a0); a1 = fmaf(v1.x, wc[4 * q + 0], a1);
      a0 = fmaf(v0.y, wc[4 * q + 1], a0); a1 = fmaf(v1.y, wc[4 * q + 1], a1);
      a0 = fmaf(v0.z, wc[4 * q + 2], a0); a1 = fmaf(v1.z, wc[4 * q + 2], a1);
      a0 = fmaf(v0.w, wc[4 * q + 3], a0); a1 = fmaf(v1.w, wc[4 * q + 3], a1);
    }
    if (c < 288) {
      G0[n * 288 + c]       = a0;
      G0[(n + 1) * 288 + c] = a1;
    } else {
      h0[n * 32 + (c - 288)]       = a0 + bi;
      h0[(n + 1) * 32 + (c - 288)] = a1 + bi;
    }
  }
}

// ---------------------------------------------------------------------------
// K2: layer-0 edge kernel. Half-wave (32 lanes) per edge.
// ---------------------------------------------------------------------------
__global__ __launch_bounds__(256) void k_edge0(
    const int* __restrict__ ei, const float* __restrict__ ea,
    const float* __restrict__ G0, float* __restrict__ h0)
{
  int tid = threadIdx.x;
  int e = blockIdx.x * 8 + (tid >> 5);
  if (e >= NE) return;
  int o = tid & 31;
  int src = ei[e], dst = ei[NE + e];
  const float* gr = G0 + src * 288;
  const float* er = ea + e * 8;
  float m = gr[256 + o];
#pragma unroll
  for (int k = 0; k < 8; ++k) m = fmaf(er[k], gr[k * 32 + o], m);
  unsafeAtomicAdd(&h0[dst * 32 + o], m);
}

// ---------------------------------------------------------------------------
// K3/K6: per-column sum & sumsq over N rows (BN stats), atomic partials.
// ---------------------------------------------------------------------------
template <int C>
__global__ __launch_bounds__(256) void k_stats(
    const float* __restrict__ h, float* __restrict__ st)
{
  const int RPB = 256 / C;
  int tid = threadIdx.x;
  int col = tid % C, rg = tid / C;
  float s1 = 0.f, s2 = 0.f;
  int step = gridDim.x * RPB;
  for (int n = blockIdx.x * RPB + rg; n < NN; n += step) {
    float v = h[n * C + col];
    s1 += v; s2 += v * v;
  }
  __shared__ float l1[256], l2[256];
  l1[tid] = s1; l2[tid] = s2;
  __syncthreads();
  if (tid < C) {
    for (int r = 1; r < RPB; ++r) { s1 += l1[r * C + tid]; s2 += l2[r * C + tid]; }
    unsafeAtomicAdd(&st[tid], s1);
    unsafeAtomicAdd(&st[C + tid], s2);
  }
}

// ---------------------------------------------------------------------------
// K4a: x1 = relu(bn0(h0)), IN-PLACE on h0 (elementwise, same thread r/w).
// ---------------------------------------------------------------------------
__global__ __launch_bounds__(256) void k_x1(
    float* __restrict__ h0, const float* __restrict__ st0,
    const float* __restrict__ g0, const float* __restrict__ be0)
{
  __shared__ float sc[32], sh[32];
  int tid = threadIdx.x;
  if (tid < 32) {
    float mu  = st0[tid] * (1.0f / NN);
    float var = st0[32 + tid] * (1.0f / NN) - mu * mu;
    float s   = g0[tid] * rsqrtf(var + BN_EPS);
    sc[tid] = s;
    sh[tid] = be0[tid] - mu * s;
  }
  __syncthreads();
  const int NV = NN * 8;  // float4 count
  for (int i = blockIdx.x * 256 + tid; i < NV; i += gridDim.x * 256) {
    float4 v = ((const float4*)h0)[i];
    int c0 = (i * 4) & 31;
    v.x = fmaxf(fmaf(v.x, sc[c0],     sh[c0]),     0.f);
    v.y = fmaxf(fmaf(v.y, sc[c0 + 1], sh[c0 + 1]), 0.f);
    v.z = fmaxf(fmaf(v.z, sc[c0 + 2], sh[c0 + 2]), 0.f);
    v.w = fmaxf(fmaf(v.w, sc[c0 + 3], sh[c0 + 3]), 0.f);
    ((float4*)h0)[i] = v;
  }
}

// ---------------------------------------------------------------------------
// K4b: layer-1 node kernel, register-column GEMV.
//  Thread t (0..319) owns output columns {2t, 2t+1}: 64 weight VGPRs from wT1
//  (coalesced float2). Per node: 8 broadcast float4 loads of x1 row + 64 fma.
//  t<288 -> G1 float2; t>=288 -> h1 float2 (+bias1). 2 nodes/iter -> 4 chains.
// ---------------------------------------------------------------------------
__global__ __launch_bounds__(320) void k_node1(
    const float* __restrict__ x1, const float* __restrict__ wT1,
    const float* __restrict__ bias1,
    float* __restrict__ G1, float* __restrict__ h1)
{
  int t = threadIdx.x;
  float wa[32], wb[32];
#pragma unroll
  for (int i = 0; i < 32; ++i) {
    float2 w2 = *(const float2*)(wT1 + i * 640 + 2 * t);
    wa[i] = w2.x; wb[i] = w2.y;
  }
  float bia = 0.f, bib = 0.f;
  if (t >= 288) { bia = bias1[2 * (t - 288)]; bib = bias1[2 * (t - 288) + 1]; }

  int n0 = blockIdx.x * 20;
  for (int n = n0; n < n0 + 20; n += 2) {
    const float4* xa = (const float4*)(x1 + n * 32);
    float a00 = 0.f, a01 = 0.f, a10 = 0.f, a11 = 0.f;
#pragma unroll
    for (int q = 0; q < 8; ++q) {
      float4 v0 = xa[q], v1 = xa[q + 8];
      a00 = fmaf(v0.x, wa[4 * q + 0], a00); a01 = fmaf(v0.x, wb[4 * q + 0], a01);
      a00 = fmaf(v0.y, wa[4 * q + 1], a00); a01 = fmaf(v0.y, wb[4 * q + 1], a01);
      a00 = fmaf(v0.z, wa[4 * q + 2], a00); a01 = fmaf(v0.z, wb[4 * q + 2], a01);
      a00 = fmaf(v0.w, wa[4 * q + 3], a00); a01 = fmaf(v0.w, wb[4 * q + 3], a01);
      a10 = fmaf(v1.x, wa[4 * q + 0], a10); a11 = fmaf(v1.x, wb[4 * q + 0], a11);
      a10 = fmaf(v1.y, wa[4 * q + 1], a10); a11 = fmaf(v1.y, wb[4 * q + 1], a11);
      a10 = fmaf(v1.z, wa[4 * q + 2], a10); a11 = fmaf(v1.z, wb[4 * q + 2], a11);
      a10 = fmaf(v1.w, wa[4 * q + 3], a10); a11 = fmaf(v1.w, wb[4 * q + 3], a11);
    }
    if (t < 288) {
      *(float2*)(G1 + n * 576 + 2 * t)       = make_float2(a00, a01);
      *(float2*)(G1 + (n + 1) * 576 + 2 * t) = make_float2(a10, a11);
    } else {
      int o = 2 * (t - 288);
      *(float2*)(h1 + n * 64 + o)       = make_float2(a00 + bia, a01 + bib);
      *(float2*)(h1 + (n + 1) * 64 + o) = make_float2(a10 + bia, a11 + bib);
    }
  }
}

// ---------------------------------------------------------------------------
// K5: layer-1 edge kernel. One wave (64 lanes) per edge.
// ---------------------------------------------------------------------------
__global__ __launch_bounds__(256) void k_edge1(
    const int* __restrict__ ei, const float* __restrict__ ea,
    const float* __restrict__ G1, float* __restrict__ h1)
{
  int tid = threadIdx.x;
  int e = blockIdx.x * 4 + (tid >> 6);
  if (e >= NE) return;
  int o = tid & 63;
  int src = ei[e], dst = ei[NE + e];
  const float* gr = G1 + src * 576;
  const float* er = ea + e * 8;
  float m = gr[512 + o];
#pragma unroll
  for (int k = 0; k < 8; ++k) m = fmaf(er[k], gr[k * 64 + o], m);
  unsafeAtomicAdd(&h1[dst * 64 + o], m);
}

// ---------------------------------------------------------------------------
// K6b: x2 = relu(bn1(h1)), IN-PLACE on h1.
// ---------------------------------------------------------------------------
__global__ __launch_bounds__(256) void k_x2(
    float* __restrict__ h1, const float* __restrict__ st1,
    const float* __restrict__ g1, const float* __restrict__ be1)
{
  __shared__ float sc[64], sh[64];
  int tid = threadIdx.x;
  if (tid < 64) {
    float mu  = st1[tid] * (1.0f / NN);
    float var = st1[64 + tid] * (1.0f / NN) - mu * mu;
    float s   = g1[tid] * rsqrtf(var + BN_EPS);
    sc[tid] = s;
    sh[tid] = be1[tid] - mu * s;
  }
  __syncthreads();
  const int NV = NN * 16;  // float4 count
  for (int i = blockIdx.x * 256 + tid; i < NV; i += gridDim.x * 256) {
    float4 v = ((const float4*)h1)[i];
    int c0 = (i * 4) & 63;
    v.x = fmaxf(fmaf(v.x, sc[c0],     sh[c0]),     0.f);
    v.y = fmaxf(fmaf(v.y, sc[c0 + 1], sh[c0 + 1]), 0.f);
    v.z = fmaxf(fmaf(v.z, sc[c0 + 2], sh[c0 + 2]), 0.f);
    v.w = fmaxf(fmaf(v.w, sc[c0 + 3], sh[c0 + 3]), 0.f);
    ((float4*)h1)[i] = v;
  }
}

// ---------------------------------------------------------------------------
// K7: head. Thread c (0..127 per 2-wave group) owns output column c in regs.
// Sorted batch -> per-thread accumulator, one atomic per boundary.
// ---------------------------------------------------------------------------
__global__ __launch_bounds__(256) void k_head(
    const float* __restrict__ x2, const float* __restrict__ wstT,
    const float* __restrict__ s_b, const float* __restrict__ t_b,
    const int* __restrict__ batch, float* __restrict__ out)
{
  int tid = threadIdx.x;
  int c = tid & 127, g = tid >> 7;
  int n0 = blockIdx.x * 40 + g * 20;
  int n1 = n0 + 20;
  if (n0 >= NN) return;
  if (n1 > NN) n1 = NN;

  float wsr[64], wtr[64];
#pragma unroll
  for (int k = 0; k < 64; ++k) {
    wsr[k] = wstT[k * 256 + c];
    wtr[k] = wstT[k * 256 + 128 + c];
  }
  float sb = s_b[c], tb = t_b[c];

  int bcur = batch[n0];
  float facc = 0.f;
  for (int n = n0; n < n1; ++n) {
    const float4* xr = (const float4*)(x2 + (size_t)n * 64);
    float as = 0.f, at = 0.f;
#pragma unroll
    for (int q = 0; q < 16; ++q) {
      float4 xv = xr[q];
      as = fmaf(xv.x, wsr[4 * q + 0], as); at = fmaf(xv.x, wtr[4 * q + 0], at);
      as = fmaf(xv.y, wsr[4 * q + 1], as); at = fmaf(xv.y, wtr[4 * q + 1], at);
      as = fmaf(xv.z, wsr[4 * q + 2], as); at = fmaf(xv.z, wtr[4 * q + 2], at);
      as = fmaf(xv.w, wsr[4 * q + 3], as); at = fmaf(xv.w, wtr[4 * q + 3], at);
    }
    float sv = fminf(30.f, fmaxf(-30.f, as + sb));
    float tv = at + tb;
    float f  = tanhf(tv) / (1.f + expf(sv));
    int b = batch[n];
    if (b != bcur) {
      unsafeAtomicAdd(&out[bcur * 128 + c], facc);
      bcur = b; facc = 0.f;
    }
    facc += f;
  }
  unsafeAtomicAdd(&out[bcur * 128 + c], facc);
}

// ---------------------------------------------------------------------------
extern "C" void kernel_launch(void* const* d_in, const int* in_sizes, int n_in,
                              void* d_out, int out_size, void* d_ws, size_t ws_size,
                              hipStream_t stream)
{
  const float* x     = (const float*)d_in[0];
  const int*   ei    = (const int*)d_in[1];
  const float* ea    = (const float*)d_in[2];
  const int*   batch = (const int*)d_in[3];
  // d_in[4] edge_batch: unused by the reference
  const float* w0    = (const float*)d_in[5];
  const float* b0    = (const float*)d_in[6];
  const float* root0 = (const float*)d_in[7];
  const float* bias0 = (const float*)d_in[8];
  const float* g0    = (const float*)d_in[9];
  const float* be0   = (const float*)d_in[10];
  const float* w1    = (const float*)d_in[11];
  const float* b1    = (const float*)d_in[12];
  const float* root1 = (const float*)d_in[13];
  const float* bias1 = (const float*)d_in[14];
  const float* g1    = (const float*)d_in[15];
  const float* be1   = (const float*)d_in[16];
  const float* s_w   = (const float*)d_in[17];
  const float* s_b   = (const float*)d_in[18];
  const float* t_w   = (const float*)d_in[19];
  const float* t_b   = (const float*)d_in[20];
  float* out = (float*)d_out;

  float* ws   = (float*)d_ws;
  float* G0   = ws;  ws += 2880000;   // N*288
  float* G1   = ws;  ws += 5760000;   // N*576
  float* h0   = ws;  ws += 320000;    // N*32   (becomes x1 in-place)
  float* h1   = ws;  ws += 640000;    // N*64   (becomes x2 in-place)
  float* st0  = ws;  ws += 64;
  float* st1  = ws;  ws += 128;
  float* wstT = ws;  ws += 16384;     // 64x256 transposed head weights
  float* wT0  = ws;  ws += 5120;      // 16x320
  float* wT1  = ws;  ws += 20480;     // 32x640

  hipLaunchKernelGGL(k_prep, dim3(64), dim3(256), 0, stream,
                     w0, b0, root0, w1, b1, root1, s_w, t_w,
                     wT0, wT1, wstT, st0, st1, out);
  hipLaunchKernelGGL(k_node0, dim3(500), dim3(320), 0, stream,
                     x, wT0, bias0, G0, h0);
  hipLaunchKernelGGL(k_edge0, dim3((NE + 7) / 8), dim3(256), 0, stream, ei, ea, G0, h0);
  hipLaunchKernelGGL(k_stats<32>, dim3(64), dim3(256), 0, stream, h0, st0);
  hipLaunchKernelGGL(k_x1, dim3(160), dim3(256), 0, stream, h0, st0, g0, be0);
  hipLaunchKernelGGL(k_node1, dim3(500), dim3(320), 0, stream,
                     h0, wT1, bias1, G1, h1);
  hipLaunchKernelGGL(k_edge1, dim3((NE + 3) / 4), dim3(256), 0, stream, ei, ea, G1, h1);
  hipLaunchKernelGGL(k_stats<64>, dim3(128), dim3(256), 0, stream, h1, st1);
  hipLaunchKernelGGL(k_x2, dim3(320), dim3(256), 0, stream, h1, st1, g1, be1);
  hipLaunchKernelGGL(k_head, dim3(250), dim3(256), 0, stream,
                     h1, wstT, s_b, t_b, batch, out);
}